// Round 4
// baseline (2561.819 us; speedup 1.0000x reference)
//
#include <hip/hip_runtime.h>
#include <math.h>

// GeneralConvNet: 3x GeneralConv + ELU, then linear->sigmoid.
// per layer: out = ELU( Adj@(x@Wm) + x@Ws + Eagg@We + deg*(bm+be) + bs )
// Bucketed sparse side: bucket = dst>>7 (128 nodes). One workgroup per bucket
// accumulates G in LDS (ds_add_f32), epilogue writes ELU(S+G) directly.
// deg/bias terms folded into the MFMA via Eagg channels 16 (deg) and 17 (1.0).

typedef __attribute__((ext_vector_type(8))) short short8;
typedef __attribute__((ext_vector_type(4))) float f32x4;

static __device__ __forceinline__ float elu_f(float v){ return v > 0.f ? v : expm1f(v); }

static __device__ __forceinline__ unsigned short f2bf_rne(float f){
  unsigned u = __float_as_uint(f);
  u += 0x7FFFu + ((u >> 16) & 1u);
  return (unsigned short)(u >> 16);
}
static __device__ __forceinline__ float bf2f(unsigned short b){
  return __uint_as_float(((unsigned)b) << 16);
}

// ---------- x f32 -> bf16 ----------
__global__ void k_cvt(const float4* __restrict__ in, ushort4* __restrict__ out, long n4){
  long t = (long)blockIdx.x * 256 + threadIdx.x;
  if (t >= n4) return;
  float4 v = in[t];
  ushort4 o; o.x = f2bf_rne(v.x); o.y = f2bf_rne(v.y); o.z = f2bf_rne(v.z); o.w = f2bf_rne(v.w);
  out[t] = o;
}

// ---------- bucket histogram ----------
__global__ void k_bhist(const int* __restrict__ ei, int* __restrict__ bkt, int E){
  int e = blockIdx.x * 256 + threadIdx.x;
  if (e < E) atomicAdd(&bkt[ei[E + e] >> 7], 1);
}

// ---------- 1-block exclusive scan over buckets ----------
__global__ __launch_bounds__(1024) void k_bscan(const int* __restrict__ bkt,
                                                int* __restrict__ bbase,
                                                int* __restrict__ bcur, int NB){
  __shared__ int sd[1024];
  int t = threadIdx.x;
  int v = (t < NB) ? bkt[t] : 0;
  sd[t] = v;
  __syncthreads();
  for (int off = 1; off < 1024; off <<= 1){
    int u = (t >= off) ? sd[t - off] : 0;
    __syncthreads();
    sd[t] += u;
    __syncthreads();
  }
  int incl = sd[t];
  int ex = incl - v;
  if (t < NB){ bbase[t] = ex; bcur[t] = ex; }
  if (t == NB - 1) bbase[NB] = incl;
}

// ---------- bucket-append scatter: tmp[pos] = {src|dl<<17, eid|dl<<21} ----------
__global__ void k_scatter(const int* __restrict__ ei, int* __restrict__ bcur,
                          int2* __restrict__ tmp, int E){
  int e = blockIdx.x * 256 + threadIdx.x;
  if (e >= E) return;
  int s = ei[e], d = ei[E + e];
  int b = d >> 7, dl = d & 127;
  int pos = atomicAdd(&bcur[b], 1);
  tmp[pos] = make_int2(s | (dl << 17), e | (dl << 21));
}

// ---------- per-bucket edge-attr aggregation + deg -> Eagg bf16 [N][32] ----------
// ch 0-15: sum edge_attr; ch16: deg; ch17: 1.0; ch18-31: 0.
__global__ __launch_bounds__(256) void k_eaggb(const float* __restrict__ eattr,
                                               const int2* __restrict__ tmp,
                                               const int* __restrict__ bbase,
                                               unsigned short* __restrict__ Eagg, int N){
  __shared__ float Ea[128][17];
  int tid = threadIdx.x;
  for (int i = tid; i < 128 * 17; i += 256) ((float*)Ea)[i] = 0.f;
  __syncthreads();
  int b = blockIdx.x;
  int s0 = bbase[b], s1 = bbase[b + 1];
  int w = tid >> 6, lane = tid & 63;
  int g = lane >> 4, cl = lane & 15;
  for (int base = s0 + (w << 2); base < s1; base += 16){
    int idx = base + g;
    if (idx < s1){
      int w1 = tmp[idx].y;
      int eid = w1 & 0x1FFFFF;
      int dl = ((unsigned)w1) >> 21;
      float v = eattr[(long)eid * 16 + cl];
      atomicAdd(&Ea[dl][cl], v);
      if (cl == 0) atomicAdd(&Ea[dl][16], 1.0f);
    }
  }
  __syncthreads();
  if (tid < 128){
    long node = ((long)b << 7) + tid;
    if (node < N){
      ushort4* o = (ushort4*)(Eagg + node * 32);
      #pragma unroll
      for (int q = 0; q < 4; ++q){
        ushort4 v;
        v.x = f2bf_rne(Ea[tid][q * 4 + 0]);
        v.y = f2bf_rne(Ea[tid][q * 4 + 1]);
        v.z = f2bf_rne(Ea[tid][q * 4 + 2]);
        v.w = f2bf_rne(Ea[tid][q * 4 + 3]);
        o[q] = v;
      }
      ushort4 v4; v4.x = f2bf_rne(Ea[tid][16]); v4.y = 0x3F80; v4.z = 0; v4.w = 0;
      o[4] = v4;
      ushort4 z; z.x = 0; z.y = 0; z.z = 0; z.w = 0;
      o[5] = z; o[6] = z; o[7] = z;
    }
  }
}

// ---------- dual MFMA GEMM: [P | S] = A @ [Wm | Ws] + Eagg @ [0 | We;bm+be;bs] ----------
__global__ __launch_bounds__(256) void k_dual(
    const unsigned short* __restrict__ A, int K,
    const unsigned short* __restrict__ Eagg,
    const float* __restrict__ Wm, const float* __restrict__ Ws, const float* __restrict__ We,
    const float* __restrict__ bm, const float* __restrict__ be, const float* __restrict__ bs,
    unsigned short* __restrict__ P, float* __restrict__ S, int N)
{
  extern __shared__ unsigned short Wt[];   // [128 cols][SW], SW = K+40
  const int SW = K + 40;
  const int tid = threadIdx.x;

  for (int idx = tid; idx < (K << 7); idx += 256){
    int k = idx >> 7, c = idx & 127;
    float v = (c < 64) ? Wm[k * 64 + c] : Ws[k * 64 + (c - 64)];
    Wt[c * SW + k] = f2bf_rne(v);
  }
  for (int idx = tid; idx < (32 << 7); idx += 256){
    int k2 = idx >> 7, c = idx & 127;
    float v = 0.f;
    if (c >= 64){
      int cc = c - 64;
      if (k2 < 16)       v = We[k2 * 64 + cc];
      else if (k2 == 16) v = bm[cc] + be[cc];
      else if (k2 == 17) v = bs[cc];
    }
    Wt[c * SW + K + k2] = f2bf_rne(v);
  }
  __syncthreads();

  const int w = tid >> 6, lane = tid & 63;
  const int wr = w & 1, wc = w >> 1;
  const int l15 = lane & 15, lg = lane >> 4;
  const long tile0 = (long)blockIdx.x * 128;

  f32x4 acc[4][4];
  #pragma unroll
  for (int a = 0; a < 4; ++a)
    #pragma unroll
    for (int bq = 0; bq < 4; ++bq)
      acc[a][bq] = (f32x4){0.f, 0.f, 0.f, 0.f};

  const int NC = (K >> 5) + 1;
  for (int kc = 0; kc < NC; ++kc){
    const unsigned short* Ap; long astr; int kin;
    if (kc < NC - 1){ Ap = A; astr = K; kin = kc * 32 + lg * 8; }
    else            { Ap = Eagg; astr = 32; kin = lg * 8; }
    short8 af[4], bfv[4];
    #pragma unroll
    for (int rt = 0; rt < 4; ++rt){
      long node = tile0 + wr * 64 + rt * 16 + l15;
      long nn = (node < N) ? node : 0;
      af[rt] = *reinterpret_cast<const short8*>(Ap + nn * astr + kin);
    }
    int kB = kc * 32 + lg * 8;
    #pragma unroll
    for (int ct = 0; ct < 4; ++ct){
      int col = wc * 64 + ct * 16 + l15;
      bfv[ct] = *reinterpret_cast<const short8*>(&Wt[col * SW + kB]);
    }
    #pragma unroll
    for (int rt = 0; rt < 4; ++rt)
      #pragma unroll
      for (int ct = 0; ct < 4; ++ct)
        acc[rt][ct] = __builtin_amdgcn_mfma_f32_16x16x32_bf16(af[rt], bfv[ct], acc[rt][ct], 0, 0, 0);
  }

  if (wc == 0){
    #pragma unroll
    for (int rt = 0; rt < 4; ++rt)
      #pragma unroll
      for (int r = 0; r < 4; ++r){
        long node = tile0 + wr * 64 + rt * 16 + lg * 4 + r;
        if (node < N){
          #pragma unroll
          for (int ct = 0; ct < 4; ++ct)
            P[node * 64 + ct * 16 + l15] = f2bf_rne(acc[rt][ct][r]);
        }
      }
  } else {
    #pragma unroll
    for (int rt = 0; rt < 4; ++rt)
      #pragma unroll
      for (int r = 0; r < 4; ++r){
        long node = tile0 + wr * 64 + rt * 16 + lg * 4 + r;
        if (node < N){
          #pragma unroll
          for (int ct = 0; ct < 4; ++ct)
            S[node * 64 + ct * 16 + l15] = acc[rt][ct][r];
        }
      }
  }
}

// ---------- fused per-bucket aggregate + combine + epilogue ----------
// LAYER: 1 -> write Hb; 2 -> write Hb + outF + outCat[0:64]; 3 -> logit/sigmoid.
template<int LAYER>
__global__ __launch_bounds__(256) void k_aggcomb(
    const unsigned short* __restrict__ P, const int2* __restrict__ tmp,
    const int* __restrict__ bbase, const float* __restrict__ S,
    unsigned short* __restrict__ Hb, float* __restrict__ outF, float* __restrict__ outCat,
    const float* __restrict__ Wl, const float* __restrict__ bl, float* __restrict__ out0,
    int N)
{
  __shared__ float Gs[128][64];   // 32 KB
  int tid = threadIdx.x;
  for (int i = tid; i < 128 * 64 / 4; i += 256)
    ((float4*)Gs)[i] = make_float4(0.f, 0.f, 0.f, 0.f);
  __syncthreads();

  int b = blockIdx.x;
  int s0 = bbase[b], s1 = bbase[b + 1];
  int w = tid >> 6, lane = tid & 63;
  for (int base = s0 + (w << 2); base < s1; base += 16){
    int nE = s1 - base; if (nE > 4) nE = 4;
    int w0[4]; unsigned short pv[4];
    #pragma unroll
    for (int j = 0; j < 4; ++j) if (j < nE) w0[j] = tmp[base + j].x;
    #pragma unroll
    for (int j = 0; j < 4; ++j) if (j < nE){
      int src = w0[j] & 0x1FFFF;
      pv[j] = P[(long)src * 64 + lane];
    }
    #pragma unroll
    for (int j = 0; j < 4; ++j) if (j < nE){
      int dl = ((unsigned)w0[j]) >> 17;
      atomicAdd(&Gs[dl][lane], bf2f(pv[j]));
    }
  }
  __syncthreads();

  int nl = tid >> 1, h = tid & 1;
  long node = ((long)b << 7) + nl;
  if (node >= N) return;
  const float4* Sp = (const float4*)(S + node * 64 + h * 32);
  float dot = 0.f;
  #pragma unroll
  for (int q = 0; q < 8; ++q){
    float4 sv = Sp[q];
    const float* gp = &Gs[nl][h * 32 + q * 4];
    float v0 = elu_f(sv.x + gp[0]);
    float v1 = elu_f(sv.y + gp[1]);
    float v2 = elu_f(sv.z + gp[2]);
    float v3 = elu_f(sv.w + gp[3]);
    int j0 = h * 32 + q * 4;
    if (LAYER == 1 || LAYER == 2){
      ushort4 o; o.x = f2bf_rne(v0); o.y = f2bf_rne(v1); o.z = f2bf_rne(v2); o.w = f2bf_rne(v3);
      *reinterpret_cast<ushort4*>(Hb + node * 64 + j0) = o;
    }
    if (LAYER == 2){
      *reinterpret_cast<float4*>(outF + node * 64 + j0) = make_float4(v0, v1, v2, v3);
      long cb = node * 65 + j0;
      outCat[cb + 0] = v0; outCat[cb + 1] = v1; outCat[cb + 2] = v2; outCat[cb + 3] = v3;
    }
    if (LAYER == 3){
      dot += v0 * Wl[j0] + v1 * Wl[j0 + 1] + v2 * Wl[j0 + 2] + v3 * Wl[j0 + 3];
    }
  }
  if (LAYER == 3){
    dot += __shfl_xor(dot, 1);
    if (h == 0){
      float logit = dot + bl[0];
      out0[node] = 1.f / (1.f + expf(-logit));
      outCat[node * 65 + 64] = logit;
    }
  }
}

extern "C" void kernel_launch(void* const* d_in, const int* in_sizes, int n_in,
                              void* d_out, int out_size, void* d_ws, size_t ws_size,
                              hipStream_t stream) {
  const int N = in_sizes[0] / 128;
  const int E = in_sizes[1] / 2;
  const int NB = (N + 127) >> 7;

  const float* x    = (const float*)d_in[0];
  const int*   ei   = (const int*)  d_in[1];
  const float* eat  = (const float*)d_in[2];
  const float* Wm1  = (const float*)d_in[3];  const float* bm1 = (const float*)d_in[4];
  const float* We1  = (const float*)d_in[5];  const float* be1 = (const float*)d_in[6];
  const float* Ws1  = (const float*)d_in[7];  const float* bs1 = (const float*)d_in[8];
  const float* Wm2  = (const float*)d_in[9];  const float* bm2 = (const float*)d_in[10];
  const float* We2  = (const float*)d_in[11]; const float* be2 = (const float*)d_in[12];
  const float* Ws2  = (const float*)d_in[13]; const float* bs2 = (const float*)d_in[14];
  const float* Wm3  = (const float*)d_in[15]; const float* bm3 = (const float*)d_in[16];
  const float* We3  = (const float*)d_in[17]; const float* be3 = (const float*)d_in[18];
  const float* Ws3  = (const float*)d_in[19]; const float* bs3 = (const float*)d_in[20];
  const float* Wl   = (const float*)d_in[21]; const float* bl  = (const float*)d_in[22];

  // workspace layout (4B units)
  int* wsi = (int*)d_ws;
  size_t o_bkt  = 0;                           // NB
  size_t o_bb   = o_bkt  + (size_t)NB;         // NB+1
  size_t o_bc   = o_bb   + (size_t)NB + 1;     // NB
  size_t o_tmp  = o_bc   + (size_t)NB;         // 2E
  size_t o_eagg = o_tmp  + (size_t)E * 2;      // 16N (bf16 [N][32])
  size_t o_P    = o_eagg + (size_t)N * 16;     // 32N (bf16 [N][64])
  size_t o_S    = o_P    + (size_t)N * 32;     // 64N (f32 [N][64])
  size_t o_xb   = o_S    + (size_t)N * 64;     // 64N (bf16 [N][128])
  size_t o_Hb   = o_xb   + (size_t)N * 64;     // 32N (bf16 [N][64])

  int* bkt   = wsi + o_bkt;
  int* bbase = wsi + o_bb;
  int* bcur  = wsi + o_bc;
  int2* tmp  = (int2*)(wsi + o_tmp);
  unsigned short* Eagg = (unsigned short*)(wsi + o_eagg);
  unsigned short* P    = (unsigned short*)(wsi + o_P);
  float* S   = (float*)(wsi + o_S);
  unsigned short* x_bf = (unsigned short*)(wsi + o_xb);
  unsigned short* Hb   = (unsigned short*)(wsi + o_Hb);

  float* out0     = (float*)d_out;                       // [N]
  float* out_feat = (float*)d_out + N;                   // [N][64]
  float* out_cat  = (float*)d_out + (size_t)N * 65;      // [N][65]

  const int gE   = (E + 255) / 256;
  const long n4x = (long)N * 32;
  const int gCVT = (int)((n4x + 255) / 256);
  const int gT   = (N + 127) / 128;

  hipMemsetAsync(bkt, 0, (size_t)NB * sizeof(int), stream);
  k_cvt    <<<gCVT, 256, 0, stream>>>((const float4*)x, (ushort4*)x_bf, n4x);
  k_bhist  <<<gE, 256, 0, stream>>>(ei, bkt, E);
  k_bscan  <<<1, 1024, 0, stream>>>(bkt, bbase, bcur, NB);
  k_scatter<<<gE, 256, 0, stream>>>(ei, bcur, tmp, E);
  k_eaggb  <<<NB, 256, 0, stream>>>(eat, tmp, bbase, Eagg, N);

  const size_t lds128 = 128 * (128 + 40) * sizeof(unsigned short);
  const size_t lds64  = 128 * (64 + 40) * sizeof(unsigned short);

  // ---- layer 1 (K=128) ----
  k_dual<<<gT, 256, lds128, stream>>>(x_bf, 128, Eagg, Wm1, Ws1, We1, bm1, be1, bs1, P, S, N);
  k_aggcomb<1><<<NB, 256, 0, stream>>>(P, tmp, bbase, S, Hb, nullptr, nullptr,
                                       nullptr, nullptr, nullptr, N);
  // ---- layer 2 (K=64) ----
  k_dual<<<gT, 256, lds64, stream>>>(Hb, 64, Eagg, Wm2, Ws2, We2, bm2, be2, bs2, P, S, N);
  k_aggcomb<2><<<NB, 256, 0, stream>>>(P, tmp, bbase, S, Hb, out_feat, out_cat,
                                       nullptr, nullptr, nullptr, N);
  // ---- layer 3 (K=64) ----
  k_dual<<<gT, 256, lds64, stream>>>(Hb, 64, Eagg, Wm3, Ws3, We3, bm3, be3, bs3, P, S, N);
  k_aggcomb<3><<<NB, 256, 0, stream>>>(P, tmp, bbase, S, nullptr, nullptr, out_cat,
                                       Wl, bl, out0, N);
}

// Round 5
// 1059.158 us; speedup vs baseline: 2.4187x; 2.4187x over previous
//
#include <hip/hip_runtime.h>
#include <math.h>

// GeneralConvNet: 3x GeneralConv + ELU, then linear->sigmoid.
// per layer: out = ELU( Adj@(x@Wm) + x@Ws + Eagg@We + deg*(bm+be) + bs )
// Node-sorted CSR built via bucket scatter + per-bucket LDS sort (write-friendly).
// deg/bias folded into MFMA via Eagg channels 16 (deg) and 17 (1.0).

typedef __attribute__((ext_vector_type(8))) short short8;
typedef __attribute__((ext_vector_type(4))) float f32x4;

static __device__ __forceinline__ float elu_f(float v){ return v > 0.f ? v : expm1f(v); }

static __device__ __forceinline__ unsigned short f2bf_rne(float f){
  unsigned u = __float_as_uint(f);
  u += 0x7FFFu + ((u >> 16) & 1u);
  return (unsigned short)(u >> 16);
}
static __device__ __forceinline__ float bf2f(unsigned short b){
  return __uint_as_float(((unsigned)b) << 16);
}

// ---------- x f32 -> bf16 ----------
__global__ void k_cvt(const float4* __restrict__ in, ushort4* __restrict__ out, long n4){
  long t = (long)blockIdx.x * 256 + threadIdx.x;
  if (t >= n4) return;
  float4 v = in[t];
  ushort4 o; o.x = f2bf_rne(v.x); o.y = f2bf_rne(v.y); o.z = f2bf_rne(v.z); o.w = f2bf_rne(v.w);
  out[t] = o;
}

// ---------- bucket histogram ----------
__global__ void k_bhist(const int* __restrict__ ei, int* __restrict__ bkt, int E){
  int e = blockIdx.x * 256 + threadIdx.x;
  if (e < E) atomicAdd(&bkt[ei[E + e] >> 7], 1);
}

// ---------- 1-block exclusive scan over buckets (NB <= 1024) ----------
__global__ __launch_bounds__(1024) void k_bscan(const int* __restrict__ bkt,
                                                int* __restrict__ bbase,
                                                int* __restrict__ bcur, int NB){
  __shared__ int sd[1024];
  int t = threadIdx.x;
  int v = (t < NB) ? bkt[t] : 0;
  sd[t] = v;
  __syncthreads();
  for (int off = 1; off < 1024; off <<= 1){
    int u = (t >= off) ? sd[t - off] : 0;
    __syncthreads();
    sd[t] += u;
    __syncthreads();
  }
  int incl = sd[t];
  int ex = incl - v;
  if (t < NB){ bbase[t] = ex; bcur[t] = ex; }
  if (t == NB - 1) bbase[NB] = incl;
}

// ---------- bucket-append scatter: tmp[pos] = {src|dl<<17, eid|dl<<21} ----------
__global__ void k_scatter(const int* __restrict__ ei, int* __restrict__ bcur,
                          int2* __restrict__ tmp, int E){
  int e = blockIdx.x * 256 + threadIdx.x;
  if (e >= E) return;
  int s = ei[e], d = ei[E + e];
  int b = d >> 7, dl = d & 127;
  int pos = atomicAdd(&bcur[b], 1);
  tmp[pos] = make_int2(s | (dl << 17), e | (dl << 21));
}

// ---------- per-bucket LDS sort -> node-sorted srcs/eids + row_start/cnt ----------
__global__ __launch_bounds__(256) void k_lsort(const int2* __restrict__ tmp,
                                               const int* __restrict__ bbase,
                                               int* __restrict__ srcs, int* __restrict__ eids,
                                               int* __restrict__ row_start, int* __restrict__ cnt,
                                               int N){
  __shared__ int hist[128];
  __shared__ int curs[128];
  __shared__ int halftot[2];
  int b = blockIdx.x, tid = threadIdx.x;
  int s0 = bbase[b], s1 = bbase[b + 1];
  if (tid < 128) hist[tid] = 0;
  __syncthreads();
  for (int i = s0 + tid; i < s1; i += 256)
    atomicAdd(&hist[((unsigned)tmp[i].x) >> 17], 1);
  __syncthreads();
  if (tid < 128){
    int lane = tid & 63;
    int v = hist[tid];
    int s = v;
    #pragma unroll
    for (int d = 1; d < 64; d <<= 1){
      int t2 = __shfl_up(s, d);
      if (lane >= d) s += t2;
    }
    if (lane == 63) halftot[tid >> 6] = s;
    curs[tid] = s - v;                 // exclusive within 64-half
  }
  __syncthreads();
  if (tid < 128){
    int e = curs[tid] + ((tid >= 64) ? halftot[0] : 0);
    curs[tid] = s0 + e;
    long node = ((long)b << 7) + tid;
    if (node < N){ row_start[node] = s0 + e; cnt[node] = hist[tid]; }
  }
  __syncthreads();
  for (int i = s0 + tid; i < s1; i += 256){
    int2 t2 = tmp[i];
    int dl = ((unsigned)t2.x) >> 17;
    int pos = atomicAdd(&curs[dl], 1);
    srcs[pos] = t2.x & 0x1FFFF;
    eids[pos] = t2.y & 0x1FFFFF;
  }
}

// ---------- edge-attr aggregation -> Eagg bf16 [N][32]; ch16=deg, ch17=1 ----------
__global__ void k_eagg(const float4* __restrict__ eattr4, const int* __restrict__ eids,
                       const int* __restrict__ row_start, const int* __restrict__ cnt,
                       unsigned short* __restrict__ Eagg, int N){
  int t = blockIdx.x * 256 + threadIdx.x;
  int i = t >> 2, q = t & 3;
  if (i >= N) return;
  int lane = threadIdx.x & 63;
  int gbase = lane & 60;
  int p0 = row_start[i], n = cnt[i];
  float4 s = make_float4(0.f, 0.f, 0.f, 0.f);
  int c = 0;
  for (; c + 4 <= n; c += 4){
    int ereg = eids[p0 + c + q];
    int e0 = __shfl(ereg, gbase + 0), e1 = __shfl(ereg, gbase + 1);
    int e2 = __shfl(ereg, gbase + 2), e3 = __shfl(ereg, gbase + 3);
    float4 v0 = eattr4[(long)e0 * 4 + q];
    float4 v1 = eattr4[(long)e1 * 4 + q];
    float4 v2 = eattr4[(long)e2 * 4 + q];
    float4 v3 = eattr4[(long)e3 * 4 + q];
    s.x += v0.x + v1.x + v2.x + v3.x;
    s.y += v0.y + v1.y + v2.y + v3.y;
    s.z += v0.z + v1.z + v2.z + v3.z;
    s.w += v0.w + v1.w + v2.w + v3.w;
  }
  if (c < n){
    int m = n - c;
    int ereg = (q < m) ? eids[p0 + c + q] : 0;
    for (int p = 0; p < m; ++p){
      int e = __shfl(ereg, gbase + p);
      float4 v = eattr4[(long)e * 4 + q];
      s.x += v.x; s.y += v.y; s.z += v.z; s.w += v.w;
    }
  }
  ushort4 o; o.x = f2bf_rne(s.x); o.y = f2bf_rne(s.y); o.z = f2bf_rne(s.z); o.w = f2bf_rne(s.w);
  *reinterpret_cast<ushort4*>(Eagg + (long)i * 32 + q * 4) = o;
  // ch16..31: {deg, 1, 0...0}
  ushort4 z;
  if (q == 0){ z.x = f2bf_rne((float)n); z.y = 0x3F80; z.z = 0; z.w = 0; }
  else       { z.x = 0; z.y = 0; z.z = 0; z.w = 0; }
  *reinterpret_cast<ushort4*>(Eagg + (long)i * 32 + 16 + q * 4) = z;
}

// ---------- 64-dim bf16 gather-aggregate: G[i] = sum_{e: dst=i} P[src(e)] ----------
// 8 lanes/node, ushort8 (16B) per lane, 8 gathers in flight.
__global__ void k_agg64(const unsigned short* __restrict__ P, const int* __restrict__ srcs,
                        const int* __restrict__ row_start, const int* __restrict__ cnt,
                        float* __restrict__ G, int N){
  int t = blockIdx.x * 256 + threadIdx.x;
  int i = t >> 3, q = t & 7;
  if (i >= N) return;
  int lane = threadIdx.x & 63;
  int gbase = lane & 56;
  int p0 = row_start[i], n = cnt[i];
  float a[8] = {0.f, 0.f, 0.f, 0.f, 0.f, 0.f, 0.f, 0.f};
  for (int c = 0; c < n; c += 8){
    int m = n - c; if (m > 8) m = 8;
    int sreg = (q < m) ? srcs[p0 + c + q] : 0;
    int sj[8];
    #pragma unroll
    for (int j = 0; j < 8; ++j) sj[j] = __shfl(sreg, gbase + j);
    short8 v[8];
    #pragma unroll
    for (int j = 0; j < 8; ++j) if (j < m)
      v[j] = *reinterpret_cast<const short8*>(P + (long)sj[j] * 64 + q * 8);
    #pragma unroll
    for (int j = 0; j < 8; ++j) if (j < m){
      #pragma unroll
      for (int k = 0; k < 8; ++k) a[k] += bf2f((unsigned short)v[j][k]);
    }
  }
  *reinterpret_cast<float4*>(G + (long)i * 64 + q * 8)     = make_float4(a[0], a[1], a[2], a[3]);
  *reinterpret_cast<float4*>(G + (long)i * 64 + q * 8 + 4) = make_float4(a[4], a[5], a[6], a[7]);
}

// ---------- dual MFMA GEMM: [P | S] = A @ [Wm | Ws] + Eagg @ [0 | We;bm+be;bs] ----------
__global__ __launch_bounds__(256) void k_dual(
    const unsigned short* __restrict__ A, int K,
    const unsigned short* __restrict__ Eagg,
    const float* __restrict__ Wm, const float* __restrict__ Ws, const float* __restrict__ We,
    const float* __restrict__ bm, const float* __restrict__ be, const float* __restrict__ bs,
    unsigned short* __restrict__ P, float* __restrict__ S, int N)
{
  extern __shared__ unsigned short Wt[];   // [128 cols][SW], SW = K+40
  const int SW = K + 40;
  const int tid = threadIdx.x;

  for (int idx = tid; idx < (K << 7); idx += 256){
    int k = idx >> 7, c = idx & 127;
    float v = (c < 64) ? Wm[k * 64 + c] : Ws[k * 64 + (c - 64)];
    Wt[c * SW + k] = f2bf_rne(v);
  }
  for (int idx = tid; idx < (32 << 7); idx += 256){
    int k2 = idx >> 7, c = idx & 127;
    float v = 0.f;
    if (c >= 64){
      int cc = c - 64;
      if (k2 < 16)       v = We[k2 * 64 + cc];
      else if (k2 == 16) v = bm[cc] + be[cc];
      else if (k2 == 17) v = bs[cc];
    }
    Wt[c * SW + K + k2] = f2bf_rne(v);
  }
  __syncthreads();

  const int w = tid >> 6, lane = tid & 63;
  const int wr = w & 1, wc = w >> 1;
  const int l15 = lane & 15, lg = lane >> 4;
  const long tile0 = (long)blockIdx.x * 128;

  f32x4 acc[4][4];
  #pragma unroll
  for (int a = 0; a < 4; ++a)
    #pragma unroll
    for (int bq = 0; bq < 4; ++bq)
      acc[a][bq] = (f32x4){0.f, 0.f, 0.f, 0.f};

  const int NC = (K >> 5) + 1;
  for (int kc = 0; kc < NC; ++kc){
    const unsigned short* Ap; long astr; int kin;
    if (kc < NC - 1){ Ap = A; astr = K; kin = kc * 32 + lg * 8; }
    else            { Ap = Eagg; astr = 32; kin = lg * 8; }
    short8 af[4], bfv[4];
    #pragma unroll
    for (int rt = 0; rt < 4; ++rt){
      long node = tile0 + wr * 64 + rt * 16 + l15;
      long nn = (node < N) ? node : 0;
      af[rt] = *reinterpret_cast<const short8*>(Ap + nn * astr + kin);
    }
    int kB = kc * 32 + lg * 8;
    #pragma unroll
    for (int ct = 0; ct < 4; ++ct){
      int col = wc * 64 + ct * 16 + l15;
      bfv[ct] = *reinterpret_cast<const short8*>(&Wt[col * SW + kB]);
    }
    #pragma unroll
    for (int rt = 0; rt < 4; ++rt)
      #pragma unroll
      for (int ct = 0; ct < 4; ++ct)
        acc[rt][ct] = __builtin_amdgcn_mfma_f32_16x16x32_bf16(af[rt], bfv[ct], acc[rt][ct], 0, 0, 0);
  }

  if (wc == 0){
    #pragma unroll
    for (int rt = 0; rt < 4; ++rt)
      #pragma unroll
      for (int r = 0; r < 4; ++r){
        long node = tile0 + wr * 64 + rt * 16 + lg * 4 + r;
        if (node < N){
          #pragma unroll
          for (int ct = 0; ct < 4; ++ct)
            P[node * 64 + ct * 16 + l15] = f2bf_rne(acc[rt][ct][r]);
        }
      }
  } else {
    #pragma unroll
    for (int rt = 0; rt < 4; ++rt)
      #pragma unroll
      for (int r = 0; r < 4; ++r){
        long node = tile0 + wr * 64 + rt * 16 + lg * 4 + r;
        if (node < N){
          #pragma unroll
          for (int ct = 0; ct < 4; ++ct)
            S[node * 64 + ct * 16 + l15] = acc[rt][ct][r];
        }
      }
  }
}

// ---------- combine: out = ELU(S + G); outputs per layer ----------
template<int LAYER>
__global__ void k_comb(const float* __restrict__ S, const float* __restrict__ G,
                       unsigned short* __restrict__ Hb,
                       float* __restrict__ outF, float* __restrict__ outCat,
                       const float* __restrict__ Wl, const float* __restrict__ bl,
                       float* __restrict__ out0, int N)
{
  int t = blockIdx.x * 256 + threadIdx.x;
  int i = t >> 4, q = t & 15;
  if (i >= N) return;
  float4 s = *reinterpret_cast<const float4*>(S + (long)i * 64 + q * 4);
  float4 g = *reinterpret_cast<const float4*>(G + (long)i * 64 + q * 4);
  float v0 = elu_f(s.x + g.x);
  float v1 = elu_f(s.y + g.y);
  float v2 = elu_f(s.z + g.z);
  float v3 = elu_f(s.w + g.w);
  if (LAYER == 1 || LAYER == 2){
    ushort4 o; o.x = f2bf_rne(v0); o.y = f2bf_rne(v1); o.z = f2bf_rne(v2); o.w = f2bf_rne(v3);
    *reinterpret_cast<ushort4*>(Hb + (long)i * 64 + q * 4) = o;
  }
  if (LAYER == 2){
    *reinterpret_cast<float4*>(outF + (long)i * 64 + q * 4) = make_float4(v0, v1, v2, v3);
    long cb = (long)i * 65 + q * 4;
    outCat[cb + 0] = v0; outCat[cb + 1] = v1; outCat[cb + 2] = v2; outCat[cb + 3] = v3;
  }
  if (LAYER == 3){
    int j0 = q * 4;
    float4 wl = *reinterpret_cast<const float4*>(Wl + j0);
    float d = v0 * wl.x + v1 * wl.y + v2 * wl.z + v3 * wl.w;
    #pragma unroll
    for (int o = 8; o; o >>= 1) d += __shfl_xor(d, o);
    if (q == 0){
      float logit = d + bl[0];
      out0[i] = 1.f / (1.f + expf(-logit));
      outCat[(long)i * 65 + 64] = logit;
    }
  }
}

extern "C" void kernel_launch(void* const* d_in, const int* in_sizes, int n_in,
                              void* d_out, int out_size, void* d_ws, size_t ws_size,
                              hipStream_t stream) {
  const int N = in_sizes[0] / 128;
  const int E = in_sizes[1] / 2;
  const int NB = (N + 127) >> 7;

  const float* x    = (const float*)d_in[0];
  const int*   ei   = (const int*)  d_in[1];
  const float* eat  = (const float*)d_in[2];
  const float* Wm1  = (const float*)d_in[3];  const float* bm1 = (const float*)d_in[4];
  const float* We1  = (const float*)d_in[5];  const float* be1 = (const float*)d_in[6];
  const float* Ws1  = (const float*)d_in[7];  const float* bs1 = (const float*)d_in[8];
  const float* Wm2  = (const float*)d_in[9];  const float* bm2 = (const float*)d_in[10];
  const float* We2  = (const float*)d_in[11]; const float* be2 = (const float*)d_in[12];
  const float* Ws2  = (const float*)d_in[13]; const float* bs2 = (const float*)d_in[14];
  const float* Wm3  = (const float*)d_in[15]; const float* bm3 = (const float*)d_in[16];
  const float* We3  = (const float*)d_in[17]; const float* be3 = (const float*)d_in[18];
  const float* Ws3  = (const float*)d_in[19]; const float* bs3 = (const float*)d_in[20];
  const float* Wl   = (const float*)d_in[21]; const float* bl  = (const float*)d_in[22];

  // workspace layout (4B units). tmp aliases S (dead until k_dual layer 1).
  int* wsi = (int*)d_ws;
  size_t o_bkt  = 0;                            // NB
  size_t o_bb   = o_bkt  + (size_t)NB;          // NB+1
  size_t o_bc   = o_bb   + (size_t)NB + 1;      // NB
  size_t o_rs   = o_bc   + (size_t)NB;          // N
  size_t o_cnt  = o_rs   + (size_t)N;           // N
  size_t o_src  = o_cnt  + (size_t)N;           // E
  size_t o_eid  = o_src  + (size_t)E;           // E
  size_t o_eagg = o_eid  + (size_t)E;           // 16N (bf16 [N][32])
  size_t o_P    = o_eagg + (size_t)N * 16;      // 32N (bf16 [N][64])
  size_t o_S    = o_P    + (size_t)N * 32;      // 64N (f32 [N][64]); tmp 2E aliases here
  size_t o_xb   = o_S    + (size_t)N * 64;      // 64N (bf16 [N][128])
  size_t o_Hb   = o_xb   + (size_t)N * 64;      // 32N (bf16 [N][64])

  int* bkt   = wsi + o_bkt;
  int* bbase = wsi + o_bb;
  int* bcur  = wsi + o_bc;
  int* row_start = wsi + o_rs;
  int* cnt   = wsi + o_cnt;
  int* srcs  = wsi + o_src;
  int* eids  = wsi + o_eid;
  unsigned short* Eagg = (unsigned short*)(wsi + o_eagg);
  unsigned short* P    = (unsigned short*)(wsi + o_P);
  float* S   = (float*)(wsi + o_S);
  int2* tmp  = (int2*)(wsi + o_S);              // alias: dead after k_lsort
  unsigned short* x_bf = (unsigned short*)(wsi + o_xb);
  unsigned short* Hb   = (unsigned short*)(wsi + o_Hb);

  float* out0     = (float*)d_out;                       // [N]
  float* out_feat = (float*)d_out + N;                   // [N][64]
  float* out_cat  = (float*)d_out + (size_t)N * 65;      // [N][65]

  const int gE   = (E + 255) / 256;
  const long n4x = (long)N * 32;
  const int gCVT = (int)((n4x + 255) / 256);
  const int gEA  = ((size_t)N * 4 + 255) / 256;
  const int gAG  = ((size_t)N * 8 + 255) / 256;
  const int gCB  = ((size_t)N * 16 + 255) / 256;
  const int gT   = (N + 127) / 128;

  hipMemsetAsync(bkt, 0, (size_t)NB * sizeof(int), stream);
  k_cvt    <<<gCVT, 256, 0, stream>>>((const float4*)x, (ushort4*)x_bf, n4x);
  k_bhist  <<<gE, 256, 0, stream>>>(ei, bkt, E);
  k_bscan  <<<1, 1024, 0, stream>>>(bkt, bbase, bcur, NB);
  k_scatter<<<gE, 256, 0, stream>>>(ei, bcur, tmp, E);
  k_lsort  <<<NB, 256, 0, stream>>>(tmp, bbase, srcs, eids, row_start, cnt, N);
  k_eagg   <<<gEA, 256, 0, stream>>>((const float4*)eat, eids, row_start, cnt, Eagg, N);

  const size_t lds128 = 128 * (128 + 40) * sizeof(unsigned short);
  const size_t lds64  = 128 * (64 + 40) * sizeof(unsigned short);

  // ---- layer 1 (K=128) ----
  k_dual<<<gT, 256, lds128, stream>>>(x_bf, 128, Eagg, Wm1, Ws1, We1, bm1, be1, bs1, P, S, N);
  k_agg64<<<gAG, 256, 0, stream>>>(P, srcs, row_start, cnt, (float*)(wsi + o_xb), N);
  k_comb<1><<<gCB, 256, 0, stream>>>(S, (const float*)(wsi + o_xb), Hb, nullptr, nullptr,
                                     nullptr, nullptr, nullptr, N);
  // ---- layer 2 (K=64) ----
  k_dual<<<gT, 256, lds64, stream>>>(Hb, 64, Eagg, Wm2, Ws2, We2, bm2, be2, bs2, P, S, N);
  k_agg64<<<gAG, 256, 0, stream>>>(P, srcs, row_start, cnt, (float*)(wsi + o_xb), N);
  k_comb<2><<<gCB, 256, 0, stream>>>(S, (const float*)(wsi + o_xb), Hb, out_feat, out_cat,
                                     nullptr, nullptr, nullptr, N);
  // ---- layer 3 (K=64) ----
  k_dual<<<gT, 256, lds64, stream>>>(Hb, 64, Eagg, Wm3, Ws3, We3, bm3, be3, bs3, P, S, N);
  k_agg64<<<gAG, 256, 0, stream>>>(P, srcs, row_start, cnt, (float*)(wsi + o_xb), N);
  k_comb<3><<<gCB, 256, 0, stream>>>(S, (const float*)(wsi + o_xb), nullptr, nullptr, out_cat,
                                     Wl, bl, out0, N);
}

// Round 7
// 527.408 us; speedup vs baseline: 4.8574x; 2.0082x over previous
//
#include <hip/hip_runtime.h>
#include <math.h>

// GeneralConvNet: 3x GeneralConv + ELU, then linear->sigmoid.
// per layer: out = ELU( Adj@(x@Wm) + x@Ws + Eagg@We + deg*(bm+be) + bs )
// CSR build: block-chunked counting scatter (LDS hist, bulk reservation) -> per-bucket
// LDS sort -> node-sorted CSR. deg/bias folded into MFMA via Eagg ch16/17.
// Gather-aggregate fused with combine epilogue (no G round-trip).

typedef __attribute__((ext_vector_type(8))) short short8;
typedef __attribute__((ext_vector_type(4))) float f32x4;

#define NBLK_SC 128   // blocks for chunked hist/scatter

static __device__ __forceinline__ float elu_f(float v){ return v > 0.f ? v : expm1f(v); }

static __device__ __forceinline__ unsigned short f2bf_rne(float f){
  unsigned u = __float_as_uint(f);
  u += 0x7FFFu + ((u >> 16) & 1u);
  return (unsigned short)(u >> 16);
}
static __device__ __forceinline__ float bf2f(unsigned short b){
  return __uint_as_float(((unsigned)b) << 16);
}

// ---------- x f32 -> bf16 ----------
__global__ void k_cvt(const float4* __restrict__ in, ushort4* __restrict__ out, long n4){
  long t = (long)blockIdx.x * 256 + threadIdx.x;
  if (t >= n4) return;
  float4 v = in[t];
  ushort4 o; o.x = f2bf_rne(v.x); o.y = f2bf_rne(v.y); o.z = f2bf_rne(v.z); o.w = f2bf_rne(v.w);
  out[t] = o;
}

// ---------- chunked bucket histogram: LDS hist + one bulk atomic per bucket ----------
__global__ __launch_bounds__(256) void k_bhist(const int* __restrict__ ei,
                                               int* __restrict__ bkt,
                                               int E, int NB, int chunk){
  __shared__ int h[1024];
  int tid = threadIdx.x;
  int b0 = blockIdx.x * chunk;
  int b1 = b0 + chunk; if (b1 > E) b1 = E;
  for (int i = tid; i < NB; i += 256) h[i] = 0;
  __syncthreads();
  for (int i = b0 + tid; i < b1; i += 256)
    atomicAdd(&h[ei[E + i] >> 7], 1);
  __syncthreads();
  for (int i = tid; i < NB; i += 256)
    if (h[i]) atomicAdd(&bkt[i], h[i]);
}

// ---------- 1-block exclusive scan over buckets (NB <= 1024) ----------
__global__ __launch_bounds__(1024) void k_bscan(const int* __restrict__ bkt,
                                                int* __restrict__ bbase,
                                                int* __restrict__ bcur, int NB){
  __shared__ int sd[1024];
  int t = threadIdx.x;
  int v = (t < NB) ? bkt[t] : 0;
  sd[t] = v;
  __syncthreads();
  for (int off = 1; off < 1024; off <<= 1){
    int u = (t >= off) ? sd[t - off] : 0;
    __syncthreads();
    sd[t] += u;
    __syncthreads();
  }
  int incl = sd[t];
  int ex = incl - v;
  if (t < NB){ bbase[t] = ex; bcur[t] = ex; }
  if (t == NB - 1) bbase[NB] = incl;
}

// ---------- chunked counting scatter: per-block LDS hist -> bulk reserve -> write ----------
__global__ __launch_bounds__(256) void k_sscat(const int* __restrict__ ei,
                                               int* __restrict__ bcur,
                                               int2* __restrict__ tmp,
                                               int E, int NB, int chunk){
  __shared__ int h[1024];
  __shared__ int base[1024];
  int tid = threadIdx.x;
  int b0 = blockIdx.x * chunk;
  int b1 = b0 + chunk; if (b1 > E) b1 = E;
  for (int i = tid; i < NB; i += 256) h[i] = 0;
  __syncthreads();
  for (int i = b0 + tid; i < b1; i += 256)
    atomicAdd(&h[ei[E + i] >> 7], 1);
  __syncthreads();
  for (int i = tid; i < NB; i += 256){
    int c = h[i];
    base[i] = c ? atomicAdd(&bcur[i], c) : 0;
    h[i] = 0;
  }
  __syncthreads();
  for (int i = b0 + tid; i < b1; i += 256){
    int s = ei[i], d = ei[E + i];
    int b = d >> 7, dl = d & 127;
    int pos = base[b] + atomicAdd(&h[b], 1);
    tmp[pos] = make_int2(s | (dl << 17), i | (dl << 21));
  }
}

// ---------- per-bucket LDS sort -> node-sorted srcs/eids + row_start/cnt ----------
__global__ __launch_bounds__(256) void k_lsort(const int2* __restrict__ tmp,
                                               const int* __restrict__ bbase,
                                               int* __restrict__ srcs, int* __restrict__ eids,
                                               int* __restrict__ row_start, int* __restrict__ cnt,
                                               int N){
  __shared__ int hist[128];
  __shared__ int curs[128];
  __shared__ int halftot[2];
  int b = blockIdx.x, tid = threadIdx.x;
  int s0 = bbase[b], s1 = bbase[b + 1];
  if (tid < 128) hist[tid] = 0;
  __syncthreads();
  for (int i = s0 + tid; i < s1; i += 256)
    atomicAdd(&hist[((unsigned)tmp[i].x) >> 17], 1);
  __syncthreads();
  if (tid < 128){
    int lane = tid & 63;
    int v = hist[tid];
    int s = v;
    #pragma unroll
    for (int d = 1; d < 64; d <<= 1){
      int t2 = __shfl_up(s, d);
      if (lane >= d) s += t2;
    }
    if (lane == 63) halftot[tid >> 6] = s;
    curs[tid] = s - v;
  }
  __syncthreads();
  if (tid < 128){
    int e = curs[tid] + ((tid >= 64) ? halftot[0] : 0);
    curs[tid] = s0 + e;
    long node = ((long)b << 7) + tid;
    if (node < N){ row_start[node] = s0 + e; cnt[node] = hist[tid]; }
  }
  __syncthreads();
  for (int i = s0 + tid; i < s1; i += 256){
    int2 t2 = tmp[i];
    int dl = ((unsigned)t2.x) >> 17;
    int pos = atomicAdd(&curs[dl], 1);
    srcs[pos] = t2.x & 0x1FFFF;
    eids[pos] = t2.y & 0x1FFFFF;
  }
}

// ---------- edge-attr aggregation -> Eagg bf16 [N][32]; ch16=deg, ch17=1 ----------
__global__ void k_eagg(const float4* __restrict__ eattr4, const int* __restrict__ eids,
                       const int* __restrict__ row_start, const int* __restrict__ cnt,
                       unsigned short* __restrict__ Eagg, int N){
  int t = blockIdx.x * 256 + threadIdx.x;
  int i = t >> 2, q = t & 3;
  if (i >= N) return;
  int lane = threadIdx.x & 63;
  int gbase = lane & 60;
  int p0 = row_start[i], n = cnt[i];
  float4 s = make_float4(0.f, 0.f, 0.f, 0.f);
  int c = 0;
  for (; c + 4 <= n; c += 4){
    int ereg = eids[p0 + c + q];
    int e0 = __shfl(ereg, gbase + 0), e1 = __shfl(ereg, gbase + 1);
    int e2 = __shfl(ereg, gbase + 2), e3 = __shfl(ereg, gbase + 3);
    float4 v0 = eattr4[(long)e0 * 4 + q];
    float4 v1 = eattr4[(long)e1 * 4 + q];
    float4 v2 = eattr4[(long)e2 * 4 + q];
    float4 v3 = eattr4[(long)e3 * 4 + q];
    s.x += v0.x + v1.x + v2.x + v3.x;
    s.y += v0.y + v1.y + v2.y + v3.y;
    s.z += v0.z + v1.z + v2.z + v3.z;
    s.w += v0.w + v1.w + v2.w + v3.w;
  }
  if (c < n){
    int m = n - c;
    int ereg = (q < m) ? eids[p0 + c + q] : 0;
    for (int p = 0; p < m; ++p){
      int e = __shfl(ereg, gbase + p);
      float4 v = eattr4[(long)e * 4 + q];
      s.x += v.x; s.y += v.y; s.z += v.z; s.w += v.w;
    }
  }
  ushort4 o; o.x = f2bf_rne(s.x); o.y = f2bf_rne(s.y); o.z = f2bf_rne(s.z); o.w = f2bf_rne(s.w);
  *reinterpret_cast<ushort4*>(Eagg + (long)i * 32 + q * 4) = o;
  ushort4 z;
  if (q == 0){ z.x = f2bf_rne((float)n); z.y = 0x3F80; z.z = 0; z.w = 0; }
  else       { z.x = 0; z.y = 0; z.z = 0; z.w = 0; }
  *reinterpret_cast<ushort4*>(Eagg + (long)i * 32 + 16 + q * 4) = z;
}

// ---------- dual MFMA GEMM: [P | S] = A @ [Wm | Ws] + Eagg @ [0 | We;bm+be;bs] ----------
__global__ __launch_bounds__(256) void k_dual(
    const unsigned short* __restrict__ A, int K,
    const unsigned short* __restrict__ Eagg,
    const float* __restrict__ Wm, const float* __restrict__ Ws, const float* __restrict__ We,
    const float* __restrict__ bm, const float* __restrict__ be, const float* __restrict__ bs,
    unsigned short* __restrict__ P, float* __restrict__ S, int N)
{
  extern __shared__ unsigned short Wt[];   // [128 cols][SW], SW = K+40
  const int SW = K + 40;
  const int tid = threadIdx.x;

  for (int idx = tid; idx < (K << 7); idx += 256){
    int k = idx >> 7, c = idx & 127;
    float v = (c < 64) ? Wm[k * 64 + c] : Ws[k * 64 + (c - 64)];
    Wt[c * SW + k] = f2bf_rne(v);
  }
  for (int idx = tid; idx < (32 << 7); idx += 256){
    int k2 = idx >> 7, c = idx & 127;
    float v = 0.f;
    if (c >= 64){
      int cc = c - 64;
      if (k2 < 16)       v = We[k2 * 64 + cc];
      else if (k2 == 16) v = bm[cc] + be[cc];
      else if (k2 == 17) v = bs[cc];
    }
    Wt[c * SW + K + k2] = f2bf_rne(v);
  }
  __syncthreads();

  const int w = tid >> 6, lane = tid & 63;
  const int wr = w & 1, wc = w >> 1;
  const int l15 = lane & 15, lg = lane >> 4;
  const long tile0 = (long)blockIdx.x * 128;

  f32x4 acc[4][4];
  #pragma unroll
  for (int a = 0; a < 4; ++a)
    #pragma unroll
    for (int bq = 0; bq < 4; ++bq)
      acc[a][bq] = (f32x4){0.f, 0.f, 0.f, 0.f};

  const int NC = (K >> 5) + 1;
  for (int kc = 0; kc < NC; ++kc){
    const unsigned short* Ap; long astr; int kin;
    if (kc < NC - 1){ Ap = A; astr = K; kin = kc * 32 + lg * 8; }
    else            { Ap = Eagg; astr = 32; kin = lg * 8; }
    short8 af[4], bfv[4];
    #pragma unroll
    for (int rt = 0; rt < 4; ++rt){
      long node = tile0 + wr * 64 + rt * 16 + l15;
      long nn = (node < N) ? node : 0;
      af[rt] = *reinterpret_cast<const short8*>(Ap + nn * astr + kin);
    }
    int kB = kc * 32 + lg * 8;
    #pragma unroll
    for (int ct = 0; ct < 4; ++ct){
      int col = wc * 64 + ct * 16 + l15;
      bfv[ct] = *reinterpret_cast<const short8*>(&Wt[col * SW + kB]);
    }
    #pragma unroll
    for (int rt = 0; rt < 4; ++rt)
      #pragma unroll
      for (int ct = 0; ct < 4; ++ct)
        acc[rt][ct] = __builtin_amdgcn_mfma_f32_16x16x32_bf16(af[rt], bfv[ct], acc[rt][ct], 0, 0, 0);
  }

  if (wc == 0){
    #pragma unroll
    for (int rt = 0; rt < 4; ++rt)
      #pragma unroll
      for (int r = 0; r < 4; ++r){
        long node = tile0 + wr * 64 + rt * 16 + lg * 4 + r;
        if (node < N){
          #pragma unroll
          for (int ct = 0; ct < 4; ++ct)
            P[node * 64 + ct * 16 + l15] = f2bf_rne(acc[rt][ct][r]);
        }
      }
  } else {
    #pragma unroll
    for (int rt = 0; rt < 4; ++rt)
      #pragma unroll
      for (int r = 0; r < 4; ++r){
        long node = tile0 + wr * 64 + rt * 16 + lg * 4 + r;
        if (node < N){
          #pragma unroll
          for (int ct = 0; ct < 4; ++ct)
            S[node * 64 + ct * 16 + l15] = acc[rt][ct][r];
        }
      }
  }
}

// ---------- fused gather-aggregate + combine epilogue ----------
// 8 lanes/node, ushort8 gathers; epilogue: v = ELU(S + G), per-layer outputs.
template<int LAYER>
__global__ void k_aggfin(const unsigned short* __restrict__ P, const int* __restrict__ srcs,
                         const int* __restrict__ row_start, const int* __restrict__ cnt,
                         const float* __restrict__ S,
                         unsigned short* __restrict__ Hb,
                         float* __restrict__ outF, float* __restrict__ outCat,
                         const float* __restrict__ Wl, const float* __restrict__ bl,
                         float* __restrict__ out0, int N){
  int t = blockIdx.x * 256 + threadIdx.x;
  int i = t >> 3, q = t & 7;
  if (i >= N) return;
  int lane = threadIdx.x & 63;
  int gbase = lane & 56;
  int p0 = row_start[i], n = cnt[i];
  float a[8] = {0.f, 0.f, 0.f, 0.f, 0.f, 0.f, 0.f, 0.f};
  for (int c = 0; c < n; c += 8){
    int m = n - c; if (m > 8) m = 8;
    int sreg = (q < m) ? srcs[p0 + c + q] : 0;
    int sj[8];
    #pragma unroll
    for (int j = 0; j < 8; ++j) sj[j] = __shfl(sreg, gbase + j);
    short8 v[8];
    #pragma unroll
    for (int j = 0; j < 8; ++j) if (j < m)
      v[j] = *reinterpret_cast<const short8*>(P + (long)sj[j] * 64 + q * 8);
    #pragma unroll
    for (int j = 0; j < 8; ++j) if (j < m){
      #pragma unroll
      for (int k = 0; k < 8; ++k) a[k] += bf2f((unsigned short)v[j][k]);
    }
  }
  float4 s0 = *reinterpret_cast<const float4*>(S + (long)i * 64 + q * 8);
  float4 s1 = *reinterpret_cast<const float4*>(S + (long)i * 64 + q * 8 + 4);
  float v0 = elu_f(s0.x + a[0]);
  float v1 = elu_f(s0.y + a[1]);
  float v2 = elu_f(s0.z + a[2]);
  float v3 = elu_f(s0.w + a[3]);
  float v4 = elu_f(s1.x + a[4]);
  float v5 = elu_f(s1.y + a[5]);
  float v6 = elu_f(s1.z + a[6]);
  float v7 = elu_f(s1.w + a[7]);
  if (LAYER == 1 || LAYER == 2){
    short8 o;
    o[0] = (short)f2bf_rne(v0); o[1] = (short)f2bf_rne(v1);
    o[2] = (short)f2bf_rne(v2); o[3] = (short)f2bf_rne(v3);
    o[4] = (short)f2bf_rne(v4); o[5] = (short)f2bf_rne(v5);
    o[6] = (short)f2bf_rne(v6); o[7] = (short)f2bf_rne(v7);
    *reinterpret_cast<short8*>(Hb + (long)i * 64 + q * 8) = o;
  }
  if (LAYER == 2){
    *reinterpret_cast<float4*>(outF + (long)i * 64 + q * 8)     = make_float4(v0, v1, v2, v3);
    *reinterpret_cast<float4*>(outF + (long)i * 64 + q * 8 + 4) = make_float4(v4, v5, v6, v7);
    long cb = (long)i * 65 + q * 8;
    outCat[cb + 0] = v0; outCat[cb + 1] = v1; outCat[cb + 2] = v2; outCat[cb + 3] = v3;
    outCat[cb + 4] = v4; outCat[cb + 5] = v5; outCat[cb + 6] = v6; outCat[cb + 7] = v7;
  }
  if (LAYER == 3){
    int j0 = q * 8;
    float d = v0 * Wl[j0] + v1 * Wl[j0 + 1] + v2 * Wl[j0 + 2] + v3 * Wl[j0 + 3]
            + v4 * Wl[j0 + 4] + v5 * Wl[j0 + 5] + v6 * Wl[j0 + 6] + v7 * Wl[j0 + 7];
    d += __shfl_xor(d, 1);
    d += __shfl_xor(d, 2);
    d += __shfl_xor(d, 4);
    if (q == 0){
      float logit = d + bl[0];
      out0[i] = 1.f / (1.f + expf(-logit));
      outCat[(long)i * 65 + 64] = logit;
    }
  }
}

extern "C" void kernel_launch(void* const* d_in, const int* in_sizes, int n_in,
                              void* d_out, int out_size, void* d_ws, size_t ws_size,
                              hipStream_t stream) {
  const int N = in_sizes[0] / 128;
  const int E = in_sizes[1] / 2;
  const int NB = (N + 127) >> 7;

  const float* x    = (const float*)d_in[0];
  const int*   ei   = (const int*)  d_in[1];
  const float* eat  = (const float*)d_in[2];
  const float* Wm1  = (const float*)d_in[3];  const float* bm1 = (const float*)d_in[4];
  const float* We1  = (const float*)d_in[5];  const float* be1 = (const float*)d_in[6];
  const float* Ws1  = (const float*)d_in[7];  const float* bs1 = (const float*)d_in[8];
  const float* Wm2  = (const float*)d_in[9];  const float* bm2 = (const float*)d_in[10];
  const float* We2  = (const float*)d_in[11]; const float* be2 = (const float*)d_in[12];
  const float* Ws2  = (const float*)d_in[13]; const float* bs2 = (const float*)d_in[14];
  const float* Wm3  = (const float*)d_in[15]; const float* bm3 = (const float*)d_in[16];
  const float* We3  = (const float*)d_in[17]; const float* be3 = (const float*)d_in[18];
  const float* Ws3  = (const float*)d_in[19]; const float* bs3 = (const float*)d_in[20];
  const float* Wl   = (const float*)d_in[21]; const float* bl  = (const float*)d_in[22];

  // workspace layout (4B units). tmp aliases S (dead until k_dual layer 1).
  int* wsi = (int*)d_ws;
  size_t o_bkt  = 0;                            // NB
  size_t o_bb   = o_bkt  + (size_t)NB;          // NB+1
  size_t o_bc   = o_bb   + (size_t)NB + 1;      // NB
  size_t o_rs   = o_bc   + (size_t)NB;          // N
  size_t o_cnt  = o_rs   + (size_t)N;           // N
  size_t o_src  = o_cnt  + (size_t)N;           // E
  size_t o_eid  = o_src  + (size_t)E;           // E
  size_t o_eagg = o_eid  + (size_t)E;           // 16N (bf16 [N][32])
  size_t o_P    = o_eagg + (size_t)N * 16;      // 32N (bf16 [N][64])
  size_t o_S    = o_P    + (size_t)N * 32;      // 64N (f32 [N][64]); tmp 2E aliases here
  size_t o_xb   = o_S    + (size_t)N * 64;      // 64N (bf16 [N][128])
  size_t o_Hb   = o_xb   + (size_t)N * 64;      // 32N (bf16 [N][64])

  int* bkt   = wsi + o_bkt;
  int* bbase = wsi + o_bb;
  int* bcur  = wsi + o_bc;
  int* row_start = wsi + o_rs;
  int* cnt   = wsi + o_cnt;
  int* srcs  = wsi + o_src;
  int* eids  = wsi + o_eid;
  unsigned short* Eagg = (unsigned short*)(wsi + o_eagg);
  unsigned short* P    = (unsigned short*)(wsi + o_P);
  float* S   = (float*)(wsi + o_S);
  int2* tmp  = (int2*)(wsi + o_S);              // alias: dead after k_lsort
  unsigned short* x_bf = (unsigned short*)(wsi + o_xb);
  unsigned short* Hb   = (unsigned short*)(wsi + o_Hb);

  float* out0     = (float*)d_out;                       // [N]
  float* out_feat = (float*)d_out + N;                   // [N][64]
  float* out_cat  = (float*)d_out + (size_t)N * 65;      // [N][65]

  const long n4x = (long)N * 32;
  const int gCVT = (int)((n4x + 255) / 256);
  const int gEA  = ((size_t)N * 4 + 255) / 256;
  const int gAG  = ((size_t)N * 8 + 255) / 256;
  const int gT   = (N + 127) / 128;
  const int chunk = (E + NBLK_SC - 1) / NBLK_SC;

  hipMemsetAsync(bkt, 0, (size_t)NB * sizeof(int), stream);
  k_cvt  <<<gCVT, 256, 0, stream>>>((const float4*)x, (ushort4*)x_bf, n4x);
  k_bhist<<<NBLK_SC, 256, 0, stream>>>(ei, bkt, E, NB, chunk);
  k_bscan<<<1, 1024, 0, stream>>>(bkt, bbase, bcur, NB);
  k_sscat<<<NBLK_SC, 256, 0, stream>>>(ei, bcur, tmp, E, NB, chunk);
  k_lsort<<<NB, 256, 0, stream>>>(tmp, bbase, srcs, eids, row_start, cnt, N);
  k_eagg <<<gEA, 256, 0, stream>>>((const float4*)eat, eids, row_start, cnt, Eagg, N);

  const size_t lds128 = 128 * (128 + 40) * sizeof(unsigned short);
  const size_t lds64  = 128 * (64 + 40) * sizeof(unsigned short);

  // ---- layer 1 (K=128) ----
  k_dual<<<gT, 256, lds128, stream>>>(x_bf, 128, Eagg, Wm1, Ws1, We1, bm1, be1, bs1, P, S, N);
  k_aggfin<1><<<gAG, 256, 0, stream>>>(P, srcs, row_start, cnt, S, Hb, nullptr, nullptr,
                                       nullptr, nullptr, nullptr, N);
  // ---- layer 2 (K=64) ----
  k_dual<<<gT, 256, lds64, stream>>>(Hb, 64, Eagg, Wm2, Ws2, We2, bm2, be2, bs2, P, S, N);
  k_aggfin<2><<<gAG, 256, 0, stream>>>(P, srcs, row_start, cnt, S, Hb, out_feat, out_cat,
                                       nullptr, nullptr, nullptr, N);
  // ---- layer 3 (K=64) ----
  k_dual<<<gT, 256, lds64, stream>>>(Hb, 64, Eagg, Wm3, Ws3, We3, bm3, be3, bs3, P, S, N);
  k_aggfin<3><<<gAG, 256, 0, stream>>>(P, srcs, row_start, cnt, S, nullptr, nullptr, out_cat,
                                       Wl, bl, out0, N);
}